// Round 2
// baseline (5717.808 us; speedup 1.0000x reference)
//
#include <hip/hip_runtime.h>
#include <hip/hip_bf16.h>
#include <cstdint>
#include <cstddef>

#define BS_   128
#define MSL_  128
#define D_    768
#define NH_   12
#define DH_   64
#define DI_   3072
#define ROWS_ (BS_ * MSL_)   // 16384

// ---------------- GEMM: C = epi(A @ B^T + bias) ----------------
// A: [M][K] row-major, B: [N][K] row-major (weights are (out,in)), C: [M][N]
// EPI: 0 = +bias; 1 = (+bias)*scale+shift; 2 = relu(+bias)
// M % 128 == 0, N % 128 == 0, K % 32 == 0 (all shapes here satisfy this)
template<int EPI>
__global__ __launch_bounds__(256, 2)
void gemm_nt(const float* __restrict__ A, const float* __restrict__ B,
             const float* __restrict__ bias, const float* __restrict__ scale,
             const float* __restrict__ shift, float* __restrict__ C,
             int M, int N, int K)
{
    __shared__ float As[32][132];   // [k][m], +4 pad
    __shared__ float Bs[32][132];   // [k][n]
    const int tid = threadIdx.x;
    const int tx = tid & 15, ty = tid >> 4;
    const int m0 = blockIdx.y * 128, n0 = blockIdx.x * 128;
    const float* Ab = A + (size_t)m0 * K;
    const float* Bb = B + (size_t)n0 * K;

    float acc[8][8];
#pragma unroll
    for (int i = 0; i < 8; ++i)
#pragma unroll
        for (int j = 0; j < 8; ++j) acc[i][j] = 0.f;

    for (int k0 = 0; k0 < K; k0 += 32) {
#pragma unroll
        for (int i = 0; i < 4; ++i) {
            const int idx = tid + i * 256;      // 0..1023
            const int row = idx >> 3;           // 0..127
            const int c4  = (idx & 7) << 2;     // 0,4,...,28
            const float4 va = *(const float4*)(Ab + (size_t)row * K + k0 + c4);
            As[c4 + 0][row] = va.x; As[c4 + 1][row] = va.y;
            As[c4 + 2][row] = va.z; As[c4 + 3][row] = va.w;
            const float4 vb = *(const float4*)(Bb + (size_t)row * K + k0 + c4);
            Bs[c4 + 0][row] = vb.x; Bs[c4 + 1][row] = vb.y;
            Bs[c4 + 2][row] = vb.z; Bs[c4 + 3][row] = vb.w;
        }
        __syncthreads();
#pragma unroll
        for (int k = 0; k < 32; ++k) {
            float a[8], b[8];
            *(float4*)&a[0] = *(const float4*)&As[k][ty << 2];
            *(float4*)&a[4] = *(const float4*)&As[k][64 + (ty << 2)];
            *(float4*)&b[0] = *(const float4*)&Bs[k][tx << 2];
            *(float4*)&b[4] = *(const float4*)&Bs[k][64 + (tx << 2)];
#pragma unroll
            for (int i = 0; i < 8; ++i)
#pragma unroll
                for (int j = 0; j < 8; ++j)
                    acc[i][j] += a[i] * b[j];
        }
        __syncthreads();
    }

#pragma unroll
    for (int i = 0; i < 8; ++i) {
        const int r = m0 + ((i < 4) ? (ty * 4 + i) : (64 + ty * 4 + (i - 4)));
#pragma unroll
        for (int jh = 0; jh < 2; ++jh) {
            const int c = n0 + jh * 64 + tx * 4;
            float4 o;
#pragma unroll
            for (int j = 0; j < 4; ++j) {
                float v = acc[i][jh * 4 + j] + bias[c + j];
                if (EPI == 1) v = v * scale[c + j] + shift[c + j];
                if (EPI == 2) v = fmaxf(v, 0.f);
                (&o.x)[j] = v;
            }
            *(float4*)(C + (size_t)r * N + c) = o;
        }
    }
}

// ---------------- Head mixing: out[b,t,h,d] = sum_s V[b,s,h,d] * M[h,s,t] ----
// One block per (h, b). Output tile: 128 t-rows x 64 d-cols.
__global__ __launch_bounds__(256)
void mix_heads(const float* __restrict__ V, const float* __restrict__ Mh,
               float* __restrict__ out)
{
    __shared__ float Ms[32][132];  // [s][t]
    __shared__ float Vs[32][68];   // [s][d]
    const int h = blockIdx.x, b = blockIdx.y;
    const int tid = threadIdx.x;
    const int tx = tid & 15, ty = tid >> 4;

    float acc[8][4];
#pragma unroll
    for (int i = 0; i < 8; ++i)
#pragma unroll
        for (int j = 0; j < 4; ++j) acc[i][j] = 0.f;

    const float* Mbase = Mh + (size_t)h * MSL_ * MSL_;
    const float* Vbase = V + (size_t)b * MSL_ * D_ + h * DH_;

    for (int s0 = 0; s0 < MSL_; s0 += 32) {
#pragma unroll
        for (int i = 0; i < 4; ++i) {
            const int idx = tid + i * 256;      // 0..1023
            const int row = idx >> 5;           // 0..31
            const int c4  = (idx & 31) << 2;    // 0..124
            *(float4*)&Ms[row][c4] =
                *(const float4*)(Mbase + (size_t)(s0 + row) * MSL_ + c4);
        }
#pragma unroll
        for (int i = 0; i < 2; ++i) {
            const int idx = tid + i * 256;      // 0..511
            const int row = idx >> 4;           // 0..31
            const int c4  = (idx & 15) << 2;    // 0..60
            *(float4*)&Vs[row][c4] =
                *(const float4*)(Vbase + (size_t)(s0 + row) * D_ + c4);
        }
        __syncthreads();
#pragma unroll
        for (int s = 0; s < 32; ++s) {
            float m8[8], v4[4];
            *(float4*)&m8[0] = *(const float4*)&Ms[s][ty * 8];
            *(float4*)&m8[4] = *(const float4*)&Ms[s][ty * 8 + 4];
            *(float4*)&v4[0] = *(const float4*)&Vs[s][tx * 4];
#pragma unroll
            for (int i = 0; i < 8; ++i)
#pragma unroll
                for (int j = 0; j < 4; ++j)
                    acc[i][j] += m8[i] * v4[j];
        }
        __syncthreads();
    }

    float* obase = out + (size_t)b * MSL_ * D_ + h * DH_ + tx * 4;
#pragma unroll
    for (int i = 0; i < 8; ++i) {
        float4 o = make_float4(acc[i][0], acc[i][1], acc[i][2], acc[i][3]);
        *(float4*)(obase + (size_t)(ty * 8 + i) * D_) = o;
    }
}

// ---------------- Classifier: logits[b,n] = h[b, t=0, :] . cls_w[n,:] + cls_b[n]
__global__ void cls_kernel(const float* __restrict__ H, const float* __restrict__ W,
                           const float* __restrict__ bias, float* __restrict__ out)
{
    const int b = blockIdx.x;
    const int lane = threadIdx.x;                 // 64 lanes
    const float* row = H + (size_t)b * MSL_ * D_; // CLS token row
    float s0 = 0.f, s1 = 0.f;
    for (int d = lane; d < D_; d += 64) {
        const float xv = row[d];
        s0 += xv * W[d];
        s1 += xv * W[D_ + d];
    }
#pragma unroll
    for (int off = 32; off > 0; off >>= 1) {
        s0 += __shfl_down(s0, off);
        s1 += __shfl_down(s1, off);
    }
    if (lane == 0) {
        out[b * 2 + 0] = s0 + bias[0];
        out[b * 2 + 1] = s1 + bias[1];
    }
}

extern "C" void kernel_launch(void* const* d_in, const int* in_sizes, int n_in,
                              void* d_out, int out_size, void* d_ws, size_t ws_size,
                              hipStream_t stream)
{
    const float* x     = (const float*)d_in[0];
    const float* M0    = (const float*)d_in[1];
    const float* M1    = (const float*)d_in[2];
    const float* Wv_w  = (const float*)d_in[3];
    const float* Wv_b  = (const float*)d_in[4];
    const float* d0_w  = (const float*)d_in[5];
    const float* d0_b  = (const float*)d_in[6];
    const float* lnw   = (const float*)d_in[7];
    const float* lnb   = (const float*)d_in[8];
    const float* ff0_w = (const float*)d_in[9];
    const float* ff0_b = (const float*)d_in[10];
    const float* ff1_w = (const float*)d_in[11];
    const float* ff1_b = (const float*)d_in[12];
    const float* lnffw = (const float*)d_in[13];
    const float* lnffb = (const float*)d_in[14];
    const float* Wv1_w = (const float*)d_in[15];
    const float* Wv1_b = (const float*)d_in[16];
    const float* d01_w = (const float*)d_in[17];
    const float* d01_b = (const float*)d_in[18];
    const float* lnw1  = (const float*)d_in[19];
    const float* lnb1  = (const float*)d_in[20];
    const float* ff01_w = (const float*)d_in[21];
    const float* ff01_b = (const float*)d_in[22];
    const float* ff11_w = (const float*)d_in[23];
    const float* ff11_b = (const float*)d_in[24];
    const float* lnffw1 = (const float*)d_in[25];
    const float* lnffb1 = (const float*)d_in[26];
    const float* cls_w  = (const float*)d_in[27];
    const float* cls_b  = (const float*)d_in[28];

    // Two ping-pong activation buffers, each ROWS_ x D_ floats (50.33 MB).
    // Total workspace requirement: 2 * NB * 4 = 100.66 MB.
    const size_t NB = (size_t)ROWS_ * D_;
    float* P = (float*)d_ws;
    float* Q = P + NB;

    const dim3 blk(256);
    const int CH = 4096;  // FFN row-chunk; CH*DI_ == NB exactly

    // One transformer block, hin -> out, using buffers X (aux) and Y.
    // Flow: V: hin->Y ; mix: Y->X ; dense0: X->Y ; FFN chunked: up Y[c]->X,
    // down X->Y[c] (in place). Result lands in Y.
    auto run_block = [&](const float* hin, float* X, float* Y, const float* Mm,
                         const float* wv_w, const float* wv_b,
                         const float* dw, const float* db,
                         const float* lw, const float* lb,
                         const float* f0w, const float* f0b,
                         const float* f1w, const float* f1b,
                         const float* lfw, const float* lfb) {
        gemm_nt<0><<<dim3(D_ / 128, ROWS_ / 128), blk, 0, stream>>>(
            hin, wv_w, wv_b, nullptr, nullptr, Y, ROWS_, D_, D_);
        mix_heads<<<dim3(NH_, BS_), blk, 0, stream>>>(Y, Mm, X);
        gemm_nt<1><<<dim3(D_ / 128, ROWS_ / 128), blk, 0, stream>>>(
            X, dw, db, lw, lb, Y, ROWS_, D_, D_);
        for (int c = 0; c < ROWS_; c += CH) {
            gemm_nt<2><<<dim3(DI_ / 128, CH / 128), blk, 0, stream>>>(
                Y + (size_t)c * D_, f0w, f0b, nullptr, nullptr, X, CH, DI_, D_);
            gemm_nt<1><<<dim3(D_ / 128, CH / 128), blk, 0, stream>>>(
                X, f1w, f1b, lfw, lfb, Y + (size_t)c * D_, CH, D_, DI_);
        }
    };

    // Block 1: x -> P (X=Q aux). Block 2: P -> Q (X=P aux).
    run_block(x, Q, P, M0, Wv_w, Wv_b, d0_w, d0_b, lnw, lnb,
              ff0_w, ff0_b, ff1_w, ff1_b, lnffw, lnffb);
    run_block(P, P, Q, M1, Wv1_w, Wv1_b, d01_w, d01_b, lnw1, lnb1,
              ff01_w, ff01_b, ff11_w, ff11_b, lnffw1, lnffb1);

    cls_kernel<<<dim3(BS_), dim3(64), 0, stream>>>(Q, cls_w, cls_b, (float*)d_out);
}

// Round 3
// 987.075 us; speedup vs baseline: 5.7927x; 5.7927x over previous
//
#include <hip/hip_runtime.h>
#include <cstdint>
#include <cstddef>

#define BS_   128
#define MSL_  128
#define D_    768
#define NH_   12
#define DH_   64
#define DI_   3072
#define ROWS_ (BS_ * MSL_)   // 16384

using bf16x8 = __attribute__((ext_vector_type(8))) __bf16;
using f32x4  = __attribute__((ext_vector_type(4))) float;

// Exact RNE f32 -> bf16 bits (matches __float2bfloat16 for finite values here).
static __device__ __forceinline__ uint16_t f2b(float f) {
    uint32_t u = __builtin_bit_cast(uint32_t, f);
    u += 0x7fffu + ((u >> 16) & 1u);
    return (uint16_t)(u >> 16);
}
static __device__ __forceinline__ float b2f(uint16_t h) {
    uint32_t u = ((uint32_t)h) << 16;
    return __builtin_bit_cast(float, u);
}

__global__ __launch_bounds__(256)
void cvt_f32_bf16(const float* __restrict__ in, uint16_t* __restrict__ out, int n4) {
    int i = blockIdx.x * blockDim.x + threadIdx.x;
    if (i >= n4) return;
    float4 v = ((const float4*)in)[i];
    ushort4 o;
    o.x = f2b(v.x); o.y = f2b(v.y); o.z = f2b(v.z); o.w = f2b(v.w);
    ((ushort4*)out)[i] = o;
}

// async global->LDS, 16B per lane. LDS dest must be wave-uniform base (+lane*16 in HW).
static __device__ __forceinline__ void gload16(const uint16_t* g, uint16_t* l) {
    __builtin_amdgcn_global_load_lds(
        (__attribute__((address_space(1))) void*)(uintptr_t)g,
        (__attribute__((address_space(3))) void*)(uintptr_t)l,
        16, 0, 0);
}

// ---------------- bf16 MFMA GEMM: C = epi(A @ B^T + bias) ----------------
// A: [M][K] bf16 row-major, B: [N][K] bf16 row-major, C: [M][N] bf16.
// bias/scale/shift fp32. EPI: 0 = +bias; 1 = (+bias)*scale+shift; 2 = relu(+bias)
// Tile 128x128, BK=32, 4 waves each computing 64x64 via 4x4 mfma_f32_16x16x32_bf16.
// LDS tiles [128 rows][32 k] bf16; 16B chunk-swizzle: phys_slot = slot ^ ((row>>1)&3)
// applied on BOTH the global source (staging) and the ds_read (involution).
template<int EPI>
__global__ __launch_bounds__(256, 2)
void gemm_bf16(const uint16_t* __restrict__ A, const uint16_t* __restrict__ B,
               const float* __restrict__ bias, const float* __restrict__ scale,
               const float* __restrict__ shift, uint16_t* __restrict__ C,
               int M, int N, int K)
{
    __shared__ __align__(16) uint16_t As[128 * 32];
    __shared__ __align__(16) uint16_t Bs[128 * 32];
    const int tid  = threadIdx.x;
    const int lane = tid & 63;
    const int w    = tid >> 6;
    const int wr   = w >> 1, wc = w & 1;     // 2x2 wave grid, each 64x64
    const int m_   = lane & 15;              // fragment row/col within 16
    const int kg   = lane >> 4;              // k-group 0..3 (8 bf16 each)
    const int m0 = blockIdx.y * 128, n0 = blockIdx.x * 128;

    f32x4 acc[4][4] = {};

    for (int k0 = 0; k0 < K; k0 += 32) {
        // ---- stage A,B tiles: 512 16B-chunks each, 2 per thread per tile ----
#pragma unroll
        for (int it = 0; it < 2; ++it) {
            const int c   = tid + it * 256;          // chunk id 0..511
            const int row = c >> 2;                  // tile row 0..127
            const int ps  = c & 3;                   // physical slot
            const int ls  = ps ^ ((row >> 1) & 3);   // logical k-slot at this row
            // wave-uniform LDS base: chunk (it*256 + w*64), in ushort units *8
            uint16_t* lA = As + (size_t)(it * 256 + (tid & 192)) * 8;
            uint16_t* lB = Bs + (size_t)(it * 256 + (tid & 192)) * 8;
            gload16(A + (size_t)(m0 + row) * K + k0 + ls * 8, lA);
            gload16(B + (size_t)(n0 + row) * K + k0 + ls * 8, lB);
        }
        __syncthreads();   // compiler drains vmcnt before s_barrier

        bf16x8 a[4], b[4];
#pragma unroll
        for (int i = 0; i < 4; ++i) {
            const int row = wr * 64 + i * 16 + m_;
            a[i] = *reinterpret_cast<const bf16x8*>(
                &As[row * 32 + (kg ^ ((row >> 1) & 3)) * 8]);
        }
#pragma unroll
        for (int j = 0; j < 4; ++j) {
            const int row = wc * 64 + j * 16 + m_;
            b[j] = *reinterpret_cast<const bf16x8*>(
                &Bs[row * 32 + (kg ^ ((row >> 1) & 3)) * 8]);
        }
#pragma unroll
        for (int i = 0; i < 4; ++i)
#pragma unroll
            for (int j = 0; j < 4; ++j)
                acc[i][j] = __builtin_amdgcn_mfma_f32_16x16x32_bf16(
                    a[i], b[j], acc[i][j], 0, 0, 0);
        __syncthreads();
    }

    // ---- epilogue: C/D layout col = lane&15, row = (lane>>4)*4 + reg ----
    const int r0 = m0 + wr * 64;
    const int c0 = n0 + wc * 64;
#pragma unroll
    for (int i = 0; i < 4; ++i) {
#pragma unroll
        for (int j = 0; j < 4; ++j) {
            const int col = c0 + j * 16 + m_;
            const float bs = bias[col];
            float sc = 0.f, sh = 0.f;
            if constexpr (EPI == 1) { sc = scale[col]; sh = shift[col]; }
#pragma unroll
            for (int r = 0; r < 4; ++r) {
                float v = acc[i][j][r] + bs;
                if constexpr (EPI == 1) v = v * sc + sh;
                if constexpr (EPI == 2) v = fmaxf(v, 0.f);
                const int rowo = r0 + i * 16 + kg * 4 + r;
                C[(size_t)rowo * N + col] = f2b(v);
            }
        }
    }
}

// ---------------- Head mixing: out[b,t,h,d] = sum_s V[b,s,h,d] * M[h,s,t] ----
// V,out bf16; M fp32. One block per (h, b); fp32 VALU accumulate (6.4 GF total).
__global__ __launch_bounds__(256)
void mix_heads(const uint16_t* __restrict__ V, const float* __restrict__ Mh,
               uint16_t* __restrict__ out)
{
    __shared__ float Ms[32][132];  // [s][t]
    __shared__ float Vs[32][68];   // [s][d]
    const int h = blockIdx.x, b = blockIdx.y;
    const int tid = threadIdx.x;
    const int tx = tid & 15, ty = tid >> 4;

    float acc[8][4] = {};

    const float* Mbase = Mh + (size_t)h * MSL_ * MSL_;
    const uint16_t* Vbase = V + (size_t)b * MSL_ * D_ + h * DH_;

    for (int s0 = 0; s0 < MSL_; s0 += 32) {
#pragma unroll
        for (int i = 0; i < 4; ++i) {
            const int idx = tid + i * 256;
            const int row = idx >> 5;
            const int c4  = (idx & 31) << 2;
            *(float4*)&Ms[row][c4] =
                *(const float4*)(Mbase + (size_t)(s0 + row) * MSL_ + c4);
        }
#pragma unroll
        for (int i = 0; i < 2; ++i) {
            const int idx = tid + i * 256;
            const int row = idx >> 4;
            const int c4  = (idx & 15) << 2;
            ushort4 v = *(const ushort4*)(Vbase + (size_t)(s0 + row) * D_ + c4);
            Vs[row][c4 + 0] = b2f(v.x); Vs[row][c4 + 1] = b2f(v.y);
            Vs[row][c4 + 2] = b2f(v.z); Vs[row][c4 + 3] = b2f(v.w);
        }
        __syncthreads();
#pragma unroll
        for (int s = 0; s < 32; ++s) {
            float m8[8], v4[4];
            *(float4*)&m8[0] = *(const float4*)&Ms[s][ty * 8];
            *(float4*)&m8[4] = *(const float4*)&Ms[s][ty * 8 + 4];
            *(float4*)&v4[0] = *(const float4*)&Vs[s][tx * 4];
#pragma unroll
            for (int i = 0; i < 8; ++i)
#pragma unroll
                for (int j = 0; j < 4; ++j)
                    acc[i][j] += m8[i] * v4[j];
        }
        __syncthreads();
    }

    uint16_t* obase = out + (size_t)b * MSL_ * D_ + h * DH_ + tx * 4;
#pragma unroll
    for (int i = 0; i < 8; ++i) {
        ushort4 o;
        o.x = f2b(acc[i][0]); o.y = f2b(acc[i][1]);
        o.z = f2b(acc[i][2]); o.w = f2b(acc[i][3]);
        *(ushort4*)(obase + (size_t)(ty * 8 + i) * D_) = o;
    }
}

// ---------------- Classifier ----------------
__global__ void cls_kernel(const uint16_t* __restrict__ H, const float* __restrict__ W,
                           const float* __restrict__ bias, float* __restrict__ out)
{
    const int b = blockIdx.x;
    const int lane = threadIdx.x;                    // 64 lanes
    const uint16_t* row = H + (size_t)b * MSL_ * D_; // CLS token row
    float s0 = 0.f, s1 = 0.f;
    for (int d = lane; d < D_; d += 64) {
        const float xv = b2f(row[d]);
        s0 += xv * W[d];
        s1 += xv * W[D_ + d];
    }
#pragma unroll
    for (int off = 32; off > 0; off >>= 1) {
        s0 += __shfl_down(s0, off);
        s1 += __shfl_down(s1, off);
    }
    if (lane == 0) {
        out[b * 2 + 0] = s0 + bias[0];
        out[b * 2 + 1] = s1 + bias[1];
    }
}

extern "C" void kernel_launch(void* const* d_in, const int* in_sizes, int n_in,
                              void* d_out, int out_size, void* d_ws, size_t ws_size,
                              hipStream_t stream)
{
    const float* x     = (const float*)d_in[0];
    const float* M0    = (const float*)d_in[1];
    const float* M1    = (const float*)d_in[2];
    const float* Wv_w  = (const float*)d_in[3];
    const float* Wv_b  = (const float*)d_in[4];
    const float* d0_w  = (const float*)d_in[5];
    const float* d0_b  = (const float*)d_in[6];
    const float* lnw   = (const float*)d_in[7];
    const float* lnb   = (const float*)d_in[8];
    const float* ff0_w = (const float*)d_in[9];
    const float* ff0_b = (const float*)d_in[10];
    const float* ff1_w = (const float*)d_in[11];
    const float* ff1_b = (const float*)d_in[12];
    const float* lnffw = (const float*)d_in[13];
    const float* lnffb = (const float*)d_in[14];
    const float* Wv1_w = (const float*)d_in[15];
    const float* Wv1_b = (const float*)d_in[16];
    const float* d01_w = (const float*)d_in[17];
    const float* d01_b = (const float*)d_in[18];
    const float* lnw1  = (const float*)d_in[19];
    const float* lnb1  = (const float*)d_in[20];
    const float* ff01_w = (const float*)d_in[21];
    const float* ff01_b = (const float*)d_in[22];
    const float* ff11_w = (const float*)d_in[23];
    const float* ff11_b = (const float*)d_in[24];
    const float* lnffw1 = (const float*)d_in[25];
    const float* lnffb1 = (const float*)d_in[26];
    const float* cls_w  = (const float*)d_in[27];
    const float* cls_b  = (const float*)d_in[28];

    // Workspace layout (bf16/ushort elements). Total = 99.09 MB < 100.66 MB (proven).
    const size_t NB = (size_t)ROWS_ * D_;   // 12,582,912
    uint16_t* P = (uint16_t*)d_ws;          // activation ping
    uint16_t* Q = P + NB;                   // activation pong
    uint16_t* F = Q + NB;                   // FFN intermediate chunk (4096 x 3072 = NB)
    uint16_t* wp = F + NB;
    uint16_t* bWv[2], *bD0[2], *bF0[2], *bF1[2];
    for (int blk = 0; blk < 2; ++blk) {
        bWv[blk] = wp; wp += (size_t)D_ * D_;
        bD0[blk] = wp; wp += (size_t)D_ * D_;
        bF0[blk] = wp; wp += (size_t)DI_ * D_;
        bF1[blk] = wp; wp += (size_t)D_ * DI_;
    }

    auto cvt = [&](const float* in, uint16_t* out, size_t n) {
        const int n4 = (int)(n / 4);
        cvt_f32_bf16<<<dim3((n4 + 255) / 256), dim3(256), 0, stream>>>(in, out, n4);
    };

    // Convert activations input + all GEMM weights to bf16 (M stays fp32).
    cvt(x, P, NB);
    cvt(Wv_w,  bWv[0], (size_t)D_ * D_);
    cvt(d0_w,  bD0[0], (size_t)D_ * D_);
    cvt(ff0_w, bF0[0], (size_t)DI_ * D_);
    cvt(ff1_w, bF1[0], (size_t)D_ * DI_);
    cvt(Wv1_w, bWv[1], (size_t)D_ * D_);
    cvt(d01_w, bD0[1], (size_t)D_ * D_);
    cvt(ff01_w, bF0[1], (size_t)DI_ * D_);
    cvt(ff11_w, bF1[1], (size_t)D_ * DI_);

    const dim3 blk256(256);
    const int CH = 4096;  // FFN row chunk; CH*DI_ == NB

    // One block: in -> (V) -> t0 -> (mix) -> t1 -> (dense0) -> t0' ... result in `io`.
    // Flow with buffers (in=X): V: X->Y ; mix: Y->X ; dense0: X->Y ; FFN on Y in chunks.
    auto run_block = [&](uint16_t* X, uint16_t* Y, const float* Mm, int bi,
                         const float* wv_b, const float* db,
                         const float* lw, const float* lb,
                         const float* f0b, const float* f1b,
                         const float* lfw, const float* lfb) {
        gemm_bf16<0><<<dim3(D_ / 128, ROWS_ / 128), blk256, 0, stream>>>(
            X, bWv[bi], wv_b, nullptr, nullptr, Y, ROWS_, D_, D_);
        mix_heads<<<dim3(NH_, BS_), blk256, 0, stream>>>(Y, Mm, X);
        gemm_bf16<1><<<dim3(D_ / 128, ROWS_ / 128), blk256, 0, stream>>>(
            X, bD0[bi], db, lw, lb, Y, ROWS_, D_, D_);
        for (int c = 0; c < ROWS_; c += CH) {
            gemm_bf16<2><<<dim3(DI_ / 128, CH / 128), blk256, 0, stream>>>(
                Y + (size_t)c * D_, bF0[bi], f0b, nullptr, nullptr, F, CH, DI_, D_);
            gemm_bf16<1><<<dim3(D_ / 128, CH / 128), blk256, 0, stream>>>(
                F, bF1[bi], f1b, lfw, lfb, Y + (size_t)c * D_, CH, D_, DI_);
        }
    };

    // Block 1: x(P) -> Q.  Block 2: Q -> P.
    run_block(P, Q, M0, 0, Wv_b, d0_b, lnw, lnb, ff0_b, ff1_b, lnffw, lnffb);
    run_block(Q, P, M1, 1, Wv1_b, d01_b, lnw1, lnb1, ff01_b, ff11_b, lnffw1, lnffb1);

    cls_kernel<<<dim3(BS_), dim3(64), 0, stream>>>(P, cls_w, cls_b, (float*)d_out);
}

// Round 4
// 687.238 us; speedup vs baseline: 8.3200x; 1.4363x over previous
//
#include <hip/hip_runtime.h>
#include <cstdint>
#include <cstddef>

#define BS_   128
#define MSL_  128
#define D_    768
#define NH_   12
#define DH_   64
#define DI_   3072
#define ROWS_ (BS_ * MSL_)   // 16384

using bf16x8 = __attribute__((ext_vector_type(8))) __bf16;
using f32x4  = __attribute__((ext_vector_type(4))) float;

// Exact RNE f32 -> bf16 bits.
static __device__ __forceinline__ uint16_t f2b(float f) {
    uint32_t u = __builtin_bit_cast(uint32_t, f);
    u += 0x7fffu + ((u >> 16) & 1u);
    return (uint16_t)(u >> 16);
}
static __device__ __forceinline__ float b2f(uint16_t h) {
    uint32_t u = ((uint32_t)h) << 16;
    return __builtin_bit_cast(float, u);
}

__global__ __launch_bounds__(256)
void cvt_f32_bf16(const float* __restrict__ in, uint16_t* __restrict__ out, int n4) {
    int i = blockIdx.x * blockDim.x + threadIdx.x;
    if (i >= n4) return;
    float4 v = ((const float4*)in)[i];
    ushort4 o;
    o.x = f2b(v.x); o.y = f2b(v.y); o.z = f2b(v.z); o.w = f2b(v.w);
    ((ushort4*)out)[i] = o;
}

// async global->LDS, 16B per lane. LDS dest is wave-uniform base (+lane*16 in HW).
static __device__ __forceinline__ void gload16(const uint16_t* g, uint16_t* l) {
    __builtin_amdgcn_global_load_lds(
        (__attribute__((address_space(1))) void*)(uintptr_t)g,
        (__attribute__((address_space(3))) void*)(uintptr_t)l,
        16, 0, 0);
}

// ---------------- bf16 MFMA GEMM: C = epi(A @ B^T + bias) ----------------
// A: [M][K] bf16 row-major, B: [N][K] bf16 row-major, C: [M][N] bf16.
// bias/scale/shift fp32. EPI: 0 = +bias; 1 = (+bias)*scale+shift; 2 = relu(+bias)
// Tile 128x128, BK=32, 4 waves each computing 64x64 via 4x4 mfma_f32_16x16x32_bf16.
// LDS [128 rows][32 k]; 16B chunk-swizzle phys_slot = slot ^ ((row>>1)&3) applied on
// BOTH the global source (staging) and the ds_read (involution, rule #21).
template<int EPI>
__global__ __launch_bounds__(256, 2)
void gemm_bf16(const uint16_t* __restrict__ A, const uint16_t* __restrict__ B,
               const float* __restrict__ bias, const float* __restrict__ scale,
               const float* __restrict__ shift, uint16_t* __restrict__ C,
               int M, int N, int K)
{
    __shared__ __align__(16) uint16_t As[128 * 32];
    __shared__ __align__(16) uint16_t Bs[128 * 32];
    const int tid  = threadIdx.x;
    const int lane = tid & 63;
    const int w    = tid >> 6;
    const int wr   = w >> 1, wc = w & 1;     // 2x2 wave grid, each 64x64
    const int m_   = lane & 15;
    const int kg   = lane >> 4;              // k-group 0..3 (8 bf16 each)
    const int m0 = blockIdx.y * 128, n0 = blockIdx.x * 128;

    f32x4 acc[4][4] = {};

    for (int k0 = 0; k0 < K; k0 += 32) {
#pragma unroll
        for (int it = 0; it < 2; ++it) {
            const int c   = tid + it * 256;          // chunk id 0..511
            const int row = c >> 2;                  // tile row 0..127
            const int ps  = c & 3;                   // physical slot
            const int ls  = ps ^ ((row >> 1) & 3);   // logical k-slot at this row
            uint16_t* lA = As + (size_t)(it * 256 + (tid & 192)) * 8;
            uint16_t* lB = Bs + (size_t)(it * 256 + (tid & 192)) * 8;
            gload16(A + (size_t)(m0 + row) * K + k0 + ls * 8, lA);
            gload16(B + (size_t)(n0 + row) * K + k0 + ls * 8, lB);
        }
        __syncthreads();

        bf16x8 a[4], b[4];
#pragma unroll
        for (int i = 0; i < 4; ++i) {
            const int row = wr * 64 + i * 16 + m_;
            a[i] = *reinterpret_cast<const bf16x8*>(
                &As[row * 32 + (kg ^ ((row >> 1) & 3)) * 8]);
        }
#pragma unroll
        for (int j = 0; j < 4; ++j) {
            const int row = wc * 64 + j * 16 + m_;
            b[j] = *reinterpret_cast<const bf16x8*>(
                &Bs[row * 32 + (kg ^ ((row >> 1) & 3)) * 8]);
        }
#pragma unroll
        for (int i = 0; i < 4; ++i)
#pragma unroll
            for (int j = 0; j < 4; ++j)
                acc[i][j] = __builtin_amdgcn_mfma_f32_16x16x32_bf16(
                    a[i], b[j], acc[i][j], 0, 0, 0);
        __syncthreads();
    }

    const int r0 = m0 + wr * 64;
    const int c0 = n0 + wc * 64;
#pragma unroll
    for (int i = 0; i < 4; ++i) {
#pragma unroll
        for (int j = 0; j < 4; ++j) {
            const int col = c0 + j * 16 + m_;
            const float bs = bias[col];
            float sc = 0.f, sh = 0.f;
            if constexpr (EPI == 1) { sc = scale[col]; sh = shift[col]; }
#pragma unroll
            for (int r = 0; r < 4; ++r) {
                float v = acc[i][j][r] + bs;
                if constexpr (EPI == 1) v = v * sc + sh;
                if constexpr (EPI == 2) v = fmaxf(v, 0.f);
                const int rowo = r0 + i * 16 + kg * 4 + r;
                C[(size_t)rowo * N + col] = f2b(v);
            }
        }
    }
}

// ---------------- Head mixing: out[b,t,h,d] = sum_s V[b,s,h,d] * M[h,s,t] ----
__global__ __launch_bounds__(256)
void mix_heads(const uint16_t* __restrict__ V, const float* __restrict__ Mh,
               uint16_t* __restrict__ out)
{
    __shared__ float Ms[32][132];  // [s][t]
    __shared__ float Vs[32][68];   // [s][d]
    const int h = blockIdx.x, b = blockIdx.y;
    const int tid = threadIdx.x;
    const int tx = tid & 15, ty = tid >> 4;

    float acc[8][4] = {};

    const float* Mbase = Mh + (size_t)h * MSL_ * MSL_;
    const uint16_t* Vbase = V + (size_t)b * MSL_ * D_ + h * DH_;

    for (int s0 = 0; s0 < MSL_; s0 += 32) {
#pragma unroll
        for (int i = 0; i < 4; ++i) {
            const int idx = tid + i * 256;
            const int row = idx >> 5;
            const int c4  = (idx & 31) << 2;
            *(float4*)&Ms[row][c4] =
                *(const float4*)(Mbase + (size_t)(s0 + row) * MSL_ + c4);
        }
#pragma unroll
        for (int i = 0; i < 2; ++i) {
            const int idx = tid + i * 256;
            const int row = idx >> 4;
            const int c4  = (idx & 15) << 2;
            ushort4 v = *(const ushort4*)(Vbase + (size_t)(s0 + row) * D_ + c4);
            Vs[row][c4 + 0] = b2f(v.x); Vs[row][c4 + 1] = b2f(v.y);
            Vs[row][c4 + 2] = b2f(v.z); Vs[row][c4 + 3] = b2f(v.w);
        }
        __syncthreads();
#pragma unroll
        for (int s = 0; s < 32; ++s) {
            float m8[8], v4[4];
            *(float4*)&m8[0] = *(const float4*)&Ms[s][ty * 8];
            *(float4*)&m8[4] = *(const float4*)&Ms[s][ty * 8 + 4];
            *(float4*)&v4[0] = *(const float4*)&Vs[s][tx * 4];
#pragma unroll
            for (int i = 0; i < 8; ++i)
#pragma unroll
                for (int j = 0; j < 4; ++j)
                    acc[i][j] += m8[i] * v4[j];
        }
        __syncthreads();
    }

    uint16_t* obase = out + (size_t)b * MSL_ * D_ + h * DH_ + tx * 4;
#pragma unroll
    for (int i = 0; i < 8; ++i) {
        ushort4 o;
        o.x = f2b(acc[i][0]); o.y = f2b(acc[i][1]);
        o.z = f2b(acc[i][2]); o.w = f2b(acc[i][3]);
        *(ushort4*)(obase + (size_t)(ty * 8 + i) * D_) = o;
    }
}

// ---------------- Classifier ----------------
__global__ void cls_kernel(const uint16_t* __restrict__ H, const float* __restrict__ W,
                           const float* __restrict__ bias, float* __restrict__ out)
{
    const int b = blockIdx.x;
    const int lane = threadIdx.x;
    const uint16_t* row = H + (size_t)b * MSL_ * D_;
    float s0 = 0.f, s1 = 0.f;
    for (int d = lane; d < D_; d += 64) {
        const float xv = b2f(row[d]);
        s0 += xv * W[d];
        s1 += xv * W[D_ + d];
    }
#pragma unroll
    for (int off = 32; off > 0; off >>= 1) {
        s0 += __shfl_down(s0, off);
        s1 += __shfl_down(s1, off);
    }
    if (lane == 0) {
        out[b * 2 + 0] = s0 + bias[0];
        out[b * 2 + 1] = s1 + bias[1];
    }
}

extern "C" void kernel_launch(void* const* d_in, const int* in_sizes, int n_in,
                              void* d_out, int out_size, void* d_ws, size_t ws_size,
                              hipStream_t stream)
{
    const float* x     = (const float*)d_in[0];
    const float* M0    = (const float*)d_in[1];
    const float* M1    = (const float*)d_in[2];
    const float* Wv_w  = (const float*)d_in[3];
    const float* Wv_b  = (const float*)d_in[4];
    const float* d0_w  = (const float*)d_in[5];
    const float* d0_b  = (const float*)d_in[6];
    const float* lnw   = (const float*)d_in[7];
    const float* lnb   = (const float*)d_in[8];
    const float* ff0_w = (const float*)d_in[9];
    const float* ff0_b = (const float*)d_in[10];
    const float* ff1_w = (const float*)d_in[11];
    const float* ff1_b = (const float*)d_in[12];
    const float* lnffw = (const float*)d_in[13];
    const float* lnffb = (const float*)d_in[14];
    const float* Wv1_w = (const float*)d_in[15];
    const float* Wv1_b = (const float*)d_in[16];
    const float* d01_w = (const float*)d_in[17];
    const float* d01_b = (const float*)d_in[18];
    const float* lnw1  = (const float*)d_in[19];
    const float* lnb1  = (const float*)d_in[20];
    const float* ff01_w = (const float*)d_in[21];
    const float* ff01_b = (const float*)d_in[22];
    const float* ff11_w = (const float*)d_in[23];
    const float* ff11_b = (const float*)d_in[24];
    const float* lnffw1 = (const float*)d_in[25];
    const float* lnffb1 = (const float*)d_in[26];
    const float* cls_w  = (const float*)d_in[27];
    const float* cls_b  = (const float*)d_in[28];

    // ---- workspace layout (ushort elements) ----
    // A0, A1, A2: activation buffers (NB each, contiguous). Weights after.
    // FULL path (ws >= ~200MB): dedicated F = 4*NB after weights, CH = 16384.
    // ALIAS path (ws >= ~99.1MB, proven available): F = [A0;A1] (contiguous 2*NB),
    //   CH = 8192. Dataflow below keeps A0,A1 dead during the FFN.
    const size_t NB = (size_t)ROWS_ * D_;           // 12,582,912
    const size_t WTOT = 2ull * (2ull * D_ * D_ + 2ull * DI_ * D_);  // 11,796,480
    uint16_t* A0 = (uint16_t*)d_ws;
    uint16_t* A1 = A0 + NB;
    uint16_t* A2 = A1 + NB;
    uint16_t* wp = A2 + NB;
    uint16_t* bWv[2], *bD0[2], *bF0[2], *bF1[2];
    for (int blk = 0; blk < 2; ++blk) {
        bWv[blk] = wp; wp += (size_t)D_ * D_;
        bD0[blk] = wp; wp += (size_t)D_ * D_;
        bF0[blk] = wp; wp += (size_t)DI_ * D_;
        bF1[blk] = wp; wp += (size_t)D_ * DI_;
    }
    const size_t used_alias = (3ull * NB + WTOT) * sizeof(uint16_t);
    const size_t need_full  = used_alias + 4ull * NB * sizeof(uint16_t);
    const bool full = (ws_size >= need_full);
    uint16_t* F = full ? wp : A0;                   // FULL: dedicated; ALIAS: [A0;A1]
    const int CH = full ? ROWS_ : (ROWS_ / 2);      // 16384 or 8192

    auto cvt = [&](const float* in, uint16_t* out, size_t n) {
        const int n4 = (int)(n / 4);
        cvt_f32_bf16<<<dim3((n4 + 255) / 256), dim3(256), 0, stream>>>(in, out, n4);
    };

    // x (bf16) lands in A2: consumed by V before anything overwrites A2.
    cvt(x, A2, NB);
    cvt(Wv_w,  bWv[0], (size_t)D_ * D_);
    cvt(d0_w,  bD0[0], (size_t)D_ * D_);
    cvt(ff0_w, bF0[0], (size_t)DI_ * D_);
    cvt(ff1_w, bF1[0], (size_t)D_ * DI_);
    cvt(Wv1_w, bWv[1], (size_t)D_ * D_);
    cvt(d01_w, bD0[1], (size_t)D_ * D_);
    cvt(ff01_w, bF0[1], (size_t)DI_ * D_);
    cvt(ff11_w, bF1[1], (size_t)D_ * DI_);

    const dim3 blk256(256);

    // Per transformer block (input & output = A2):
    //   V: A2->A0 ; mix: A0->A1 ; dense0: A1->A2 ; FFN chunks on A2 (A0,A1 dead).
    auto run_block = [&](const float* Mm, int bi,
                         const float* wv_b, const float* db,
                         const float* lw, const float* lb,
                         const float* f0b, const float* f1b,
                         const float* lfw, const float* lfb) {
        gemm_bf16<0><<<dim3(D_ / 128, ROWS_ / 128), blk256, 0, stream>>>(
            A2, bWv[bi], wv_b, nullptr, nullptr, A0, ROWS_, D_, D_);
        mix_heads<<<dim3(NH_, BS_), blk256, 0, stream>>>(A0, Mm, A1);
        gemm_bf16<1><<<dim3(D_ / 128, ROWS_ / 128), blk256, 0, stream>>>(
            A1, bD0[bi], db, lw, lb, A2, ROWS_, D_, D_);
        for (int c = 0; c < ROWS_; c += CH) {
            gemm_bf16<2><<<dim3(DI_ / 128, CH / 128), blk256, 0, stream>>>(
                A2 + (size_t)c * D_, bF0[bi], f0b, nullptr, nullptr, F, CH, DI_, D_);
            gemm_bf16<1><<<dim3(D_ / 128, CH / 128), blk256, 0, stream>>>(
                F, bF1[bi], f1b, lfw, lfb, A2 + (size_t)c * D_, CH, D_, DI_);
        }
    };

    run_block(M0, 0, Wv_b, d0_b, lnw, lnb, ff0_b, ff1_b, lnffw, lnffb);
    run_block(M1, 1, Wv1_b, d01_b, lnw1, lnb1, ff01_b, ff11_b, lnffw1, lnffb1);

    cls_kernel<<<dim3(BS_), dim3(64), 0, stream>>>(A2, cls_w, cls_b, (float*)d_out);
}

// Round 5
// 644.738 us; speedup vs baseline: 8.8684x; 1.0659x over previous
//
#include <hip/hip_runtime.h>
#include <cstdint>
#include <cstddef>

#define BS_   128
#define MSL_  128
#define D_    768
#define NH_   12
#define DH_   64
#define DI_   3072
#define ROWS_ (BS_ * MSL_)   // 16384

using bf16x8 = __attribute__((ext_vector_type(8))) __bf16;
using f32x4  = __attribute__((ext_vector_type(4))) float;

// Exact RNE f32 -> bf16 bits.
static __device__ __forceinline__ uint16_t f2b(float f) {
    uint32_t u = __builtin_bit_cast(uint32_t, f);
    u += 0x7fffu + ((u >> 16) & 1u);
    return (uint16_t)(u >> 16);
}
static __device__ __forceinline__ float b2f(uint16_t h) {
    uint32_t u = ((uint32_t)h) << 16;
    return __builtin_bit_cast(float, u);
}

__global__ __launch_bounds__(256)
void cvt_f32_bf16(const float* __restrict__ in, uint16_t* __restrict__ out, int n4) {
    int i = blockIdx.x * blockDim.x + threadIdx.x;
    if (i >= n4) return;
    float4 v = ((const float4*)in)[i];
    ushort4 o;
    o.x = f2b(v.x); o.y = f2b(v.y); o.z = f2b(v.z); o.w = f2b(v.w);
    ((ushort4*)out)[i] = o;
}

// async global->LDS, 16B per lane. LDS dest is wave-uniform base (+lane*16 in HW).
static __device__ __forceinline__ void gload16(const uint16_t* g, uint16_t* l) {
    __builtin_amdgcn_global_load_lds(
        (__attribute__((address_space(1))) void*)(uintptr_t)g,
        (__attribute__((address_space(3))) void*)(uintptr_t)l,
        16, 0, 0);
}

// ---------------- bf16 MFMA GEMM: C = epi(A @ B^T + bias) ----------------
// A: [M][K] bf16 row-major, B: [N][K] bf16 row-major, C: [M][N] bf16.
// EPI: 0 = +bias; 1 = (+bias)*scale+shift; 2 = relu(+bias)
// 128x128 tile, BK=32, 4 waves x (4x4 mfma_f32_16x16x32_bf16).
// 1D grid + bijective XCD swizzle (T1): each XCD owns a contiguous wg chunk,
// n-fastest, so column-blocks sharing an A row-panel land on one XCD's L2.
// Double-buffered LDS (2-phase): STAGE(next) issued before compute(cur);
// one __syncthreads per K-step (drains vmcnt+lgkm, then barrier).
// 16B chunk-swizzle phys_slot = slot ^ ((row>>1)&3) on BOTH source and ds_read.
template<int EPI>
__global__ __launch_bounds__(256, 2)
void gemm_bf16(const uint16_t* __restrict__ A, const uint16_t* __restrict__ B,
               const float* __restrict__ bias, const float* __restrict__ scale,
               const float* __restrict__ shift, uint16_t* __restrict__ C,
               int M, int N, int K, int gx)
{
    __shared__ __align__(16) uint16_t As[2][128 * 32];
    __shared__ __align__(16) uint16_t Bs[2][128 * 32];
    const int tid  = threadIdx.x;
    const int lane = tid & 63;
    const int w    = tid >> 6;
    const int wr   = w >> 1, wc = w & 1;     // 2x2 wave grid, each 64x64
    const int m_   = lane & 15;
    const int kg   = lane >> 4;              // k-group 0..3 (8 bf16 each)

    // T1 swizzle (nwg % 8 == 0 for all grids used here): XCD xcd gets wgs
    // [xcd*q, (xcd+1)*q), preserving n-fastest order within the chunk.
    const int nwg = gridDim.x;
    const int q   = nwg >> 3;
    const int wg  = (blockIdx.x & 7) * q + (blockIdx.x >> 3);
    const int m0  = (wg / gx) * 128;
    const int n0  = (wg % gx) * 128;

    f32x4 acc[4][4] = {};

    const int row_l = (tid + 0) >> 2;          // staging rows for it=0/1
    const int row_h = (tid + 256) >> 2;
    const int ls_l  = (tid & 3) ^ ((row_l >> 1) & 3);
    const int ls_h  = (tid & 3) ^ ((row_h >> 1) & 3);
    const int base_l = ((tid & 192)) * 8;          // chunk (w*64)*16B, ushort units
    const int base_h = (256 + (tid & 192)) * 8;

    auto stage = [&](int buf, int k0) {
        gload16(A + (size_t)(m0 + row_l) * K + k0 + ls_l * 8, &As[buf][base_l]);
        gload16(B + (size_t)(n0 + row_l) * K + k0 + ls_l * 8, &Bs[buf][base_l]);
        gload16(A + (size_t)(m0 + row_h) * K + k0 + ls_h * 8, &As[buf][base_h]);
        gload16(B + (size_t)(n0 + row_h) * K + k0 + ls_h * 8, &Bs[buf][base_h]);
    };

    stage(0, 0);
    int cur = 0;
    for (int k0 = 0; k0 < K; k0 += 32) {
        __syncthreads();                 // buf[cur] staged for all waves
        if (k0 + 32 < K) stage(cur ^ 1, k0 + 32);   // async prefetch next tile

        bf16x8 a[4], b[4];
#pragma unroll
        for (int i = 0; i < 4; ++i) {
            const int row = wr * 64 + i * 16 + m_;
            a[i] = *reinterpret_cast<const bf16x8*>(
                &As[cur][row * 32 + (kg ^ ((row >> 1) & 3)) * 8]);
        }
#pragma unroll
        for (int j = 0; j < 4; ++j) {
            const int row = wc * 64 + j * 16 + m_;
            b[j] = *reinterpret_cast<const bf16x8*>(
                &Bs[cur][row * 32 + (kg ^ ((row >> 1) & 3)) * 8]);
        }
#pragma unroll
        for (int i = 0; i < 4; ++i)
#pragma unroll
            for (int j = 0; j < 4; ++j)
                acc[i][j] = __builtin_amdgcn_mfma_f32_16x16x32_bf16(
                    a[i], b[j], acc[i][j], 0, 0, 0);
        cur ^= 1;
    }

    const int r0 = m0 + wr * 64;
    const int c0 = n0 + wc * 64;
#pragma unroll
    for (int i = 0; i < 4; ++i) {
#pragma unroll
        for (int j = 0; j < 4; ++j) {
            const int col = c0 + j * 16 + m_;
            const float bs = bias[col];
            float sc = 0.f, sh = 0.f;
            if constexpr (EPI == 1) { sc = scale[col]; sh = shift[col]; }
#pragma unroll
            for (int r = 0; r < 4; ++r) {
                float v = acc[i][j][r] + bs;
                if constexpr (EPI == 1) v = v * sc + sh;
                if constexpr (EPI == 2) v = fmaxf(v, 0.f);
                const int rowo = r0 + i * 16 + kg * 4 + r;
                C[(size_t)rowo * N + col] = f2b(v);
            }
        }
    }
}

// ---------------- Head mixing: out[b,t,h,d] = sum_s V[b,s,h,d] * M[h,s,t] ----
__global__ __launch_bounds__(256)
void mix_heads(const uint16_t* __restrict__ V, const float* __restrict__ Mh,
               uint16_t* __restrict__ out)
{
    __shared__ float Ms[32][132];  // [s][t]
    __shared__ float Vs[32][68];   // [s][d]
    const int h = blockIdx.x, b = blockIdx.y;
    const int tid = threadIdx.x;
    const int tx = tid & 15, ty = tid >> 4;

    float acc[8][4] = {};

    const float* Mbase = Mh + (size_t)h * MSL_ * MSL_;
    const uint16_t* Vbase = V + (size_t)b * MSL_ * D_ + h * DH_;

    for (int s0 = 0; s0 < MSL_; s0 += 32) {
#pragma unroll
        for (int i = 0; i < 4; ++i) {
            const int idx = tid + i * 256;
            const int row = idx >> 5;
            const int c4  = (idx & 31) << 2;
            *(float4*)&Ms[row][c4] =
                *(const float4*)(Mbase + (size_t)(s0 + row) * MSL_ + c4);
        }
#pragma unroll
        for (int i = 0; i < 2; ++i) {
            const int idx = tid + i * 256;
            const int row = idx >> 4;
            const int c4  = (idx & 15) << 2;
            ushort4 v = *(const ushort4*)(Vbase + (size_t)(s0 + row) * D_ + c4);
            Vs[row][c4 + 0] = b2f(v.x); Vs[row][c4 + 1] = b2f(v.y);
            Vs[row][c4 + 2] = b2f(v.z); Vs[row][c4 + 3] = b2f(v.w);
        }
        __syncthreads();
#pragma unroll
        for (int s = 0; s < 32; ++s) {
            float m8[8], v4[4];
            *(float4*)&m8[0] = *(const float4*)&Ms[s][ty * 8];
            *(float4*)&m8[4] = *(const float4*)&Ms[s][ty * 8 + 4];
            *(float4*)&v4[0] = *(const float4*)&Vs[s][tx * 4];
#pragma unroll
            for (int i = 0; i < 8; ++i)
#pragma unroll
                for (int j = 0; j < 4; ++j)
                    acc[i][j] += m8[i] * v4[j];
        }
        __syncthreads();
    }

    uint16_t* obase = out + (size_t)b * MSL_ * D_ + h * DH_ + tx * 4;
#pragma unroll
    for (int i = 0; i < 8; ++i) {
        ushort4 o;
        o.x = f2b(acc[i][0]); o.y = f2b(acc[i][1]);
        o.z = f2b(acc[i][2]); o.w = f2b(acc[i][3]);
        *(ushort4*)(obase + (size_t)(ty * 8 + i) * D_) = o;
    }
}

// ---------------- Classifier ----------------
__global__ void cls_kernel(const uint16_t* __restrict__ H, const float* __restrict__ W,
                           const float* __restrict__ bias, float* __restrict__ out)
{
    const int b = blockIdx.x;
    const int lane = threadIdx.x;
    const uint16_t* row = H + (size_t)b * MSL_ * D_;
    float s0 = 0.f, s1 = 0.f;
    for (int d = lane; d < D_; d += 64) {
        const float xv = b2f(row[d]);
        s0 += xv * W[d];
        s1 += xv * W[D_ + d];
    }
#pragma unroll
    for (int off = 32; off > 0; off >>= 1) {
        s0 += __shfl_down(s0, off);
        s1 += __shfl_down(s1, off);
    }
    if (lane == 0) {
        out[b * 2 + 0] = s0 + bias[0];
        out[b * 2 + 1] = s1 + bias[1];
    }
}

extern "C" void kernel_launch(void* const* d_in, const int* in_sizes, int n_in,
                              void* d_out, int out_size, void* d_ws, size_t ws_size,
                              hipStream_t stream)
{
    const float* x     = (const float*)d_in[0];
    const float* M0    = (const float*)d_in[1];
    const float* M1    = (const float*)d_in[2];
    const float* Wv_w  = (const float*)d_in[3];
    const float* Wv_b  = (const float*)d_in[4];
    const float* d0_w  = (const float*)d_in[5];
    const float* d0_b  = (const float*)d_in[6];
    const float* lnw   = (const float*)d_in[7];
    const float* lnb   = (const float*)d_in[8];
    const float* ff0_w = (const float*)d_in[9];
    const float* ff0_b = (const float*)d_in[10];
    const float* ff1_w = (const float*)d_in[11];
    const float* ff1_b = (const float*)d_in[12];
    const float* lnffw = (const float*)d_in[13];
    const float* lnffb = (const float*)d_in[14];
    const float* Wv1_w = (const float*)d_in[15];
    const float* Wv1_b = (const float*)d_in[16];
    const float* d01_w = (const float*)d_in[17];
    const float* d01_b = (const float*)d_in[18];
    const float* lnw1  = (const float*)d_in[19];
    const float* lnb1  = (const float*)d_in[20];
    const float* ff01_w = (const float*)d_in[21];
    const float* ff01_b = (const float*)d_in[22];
    const float* ff11_w = (const float*)d_in[23];
    const float* ff11_b = (const float*)d_in[24];
    const float* lnffw1 = (const float*)d_in[25];
    const float* lnffb1 = (const float*)d_in[26];
    const float* cls_w  = (const float*)d_in[27];
    const float* cls_b  = (const float*)d_in[28];

    // ---- workspace layout (ushort elements) ----
    const size_t NB = (size_t)ROWS_ * D_;           // 12,582,912
    const size_t WTOT = 2ull * (2ull * D_ * D_ + 2ull * DI_ * D_);  // 11,796,480
    uint16_t* A0 = (uint16_t*)d_ws;
    uint16_t* A1 = A0 + NB;
    uint16_t* A2 = A1 + NB;
    uint16_t* wp = A2 + NB;
    uint16_t* bWv[2], *bD0[2], *bF0[2], *bF1[2];
    for (int blk = 0; blk < 2; ++blk) {
        bWv[blk] = wp; wp += (size_t)D_ * D_;
        bD0[blk] = wp; wp += (size_t)D_ * D_;
        bF0[blk] = wp; wp += (size_t)DI_ * D_;
        bF1[blk] = wp; wp += (size_t)D_ * DI_;
    }
    const size_t used_alias = (3ull * NB + WTOT) * sizeof(uint16_t);
    const size_t need_full  = used_alias + 4ull * NB * sizeof(uint16_t);
    const bool full = (ws_size >= need_full);
    uint16_t* F = full ? wp : A0;                   // FULL: dedicated; ALIAS: [A0;A1]
    const int CH = full ? ROWS_ : (ROWS_ / 2);      // 16384 or 8192

    auto cvt = [&](const float* in, uint16_t* out, size_t n) {
        const int n4 = (int)(n / 4);
        cvt_f32_bf16<<<dim3((n4 + 255) / 256), dim3(256), 0, stream>>>(in, out, n4);
    };

    cvt(x, A2, NB);
    cvt(Wv_w,  bWv[0], (size_t)D_ * D_);
    cvt(d0_w,  bD0[0], (size_t)D_ * D_);
    cvt(ff0_w, bF0[0], (size_t)DI_ * D_);
    cvt(ff1_w, bF1[0], (size_t)D_ * DI_);
    cvt(Wv1_w, bWv[1], (size_t)D_ * D_);
    cvt(d01_w, bD0[1], (size_t)D_ * D_);
    cvt(ff01_w, bF0[1], (size_t)DI_ * D_);
    cvt(ff11_w, bF1[1], (size_t)D_ * DI_);

    const dim3 blk256(256);

    auto gemm = [&](int EPI, const uint16_t* Ain, const uint16_t* Bw,
                    const float* bias, const float* sc, const float* sh,
                    uint16_t* Cout, int M, int N, int K) {
        const int gx = N / 128;
        const dim3 grid(gx * (M / 128));
        if (EPI == 0)
            gemm_bf16<0><<<grid, blk256, 0, stream>>>(Ain, Bw, bias, sc, sh, Cout, M, N, K, gx);
        else if (EPI == 1)
            gemm_bf16<1><<<grid, blk256, 0, stream>>>(Ain, Bw, bias, sc, sh, Cout, M, N, K, gx);
        else
            gemm_bf16<2><<<grid, blk256, 0, stream>>>(Ain, Bw, bias, sc, sh, Cout, M, N, K, gx);
    };

    // Per transformer block (input & output = A2):
    //   V: A2->A0 ; mix: A0->A1 ; dense0: A1->A2 ; FFN chunks on A2 (A0,A1 dead).
    auto run_block = [&](const float* Mm, int bi,
                         const float* wv_b, const float* db,
                         const float* lw, const float* lb,
                         const float* f0b, const float* f1b,
                         const float* lfw, const float* lfb) {
        gemm(0, A2, bWv[bi], wv_b, nullptr, nullptr, A0, ROWS_, D_, D_);
        mix_heads<<<dim3(NH_, BS_), blk256, 0, stream>>>(A0, Mm, A1);
        gemm(1, A1, bD0[bi], db, lw, lb, A2, ROWS_, D_, D_);
        for (int c = 0; c < ROWS_; c += CH) {
            gemm(2, A2 + (size_t)c * D_, bF0[bi], f0b, nullptr, nullptr, F, CH, DI_, D_);
            gemm(1, F, bF1[bi], f1b, lfw, lfb, A2 + (size_t)c * D_, CH, D_, DI_);
        }
    };

    run_block(M0, 0, Wv_b, d0_b, lnw, lnb, ff0_b, ff1_b, lnffw, lnffb);
    run_block(M1, 1, Wv1_b, d01_b, lnw1, lnb1, ff01_b, ff11_b, lnffw1, lnffb1);

    cls_kernel<<<dim3(BS_), dim3(64), 0, stream>>>(A2, cls_w, cls_b, (float*)d_out);
}

// Round 6
// 596.844 us; speedup vs baseline: 9.5801x; 1.0802x over previous
//
#include <hip/hip_runtime.h>
#include <cstdint>
#include <cstddef>

#define BS_   128
#define MSL_  128
#define D_    768
#define NH_   12
#define DH_   64
#define DI_   3072
#define ROWS_ (BS_ * MSL_)   // 16384

using bf16x8 = __attribute__((ext_vector_type(8))) __bf16;
using f32x4  = __attribute__((ext_vector_type(4))) float;

// Exact RNE f32 -> bf16 bits.
static __device__ __forceinline__ uint16_t f2b(float f) {
    uint32_t u = __builtin_bit_cast(uint32_t, f);
    u += 0x7fffu + ((u >> 16) & 1u);
    return (uint16_t)(u >> 16);
}
static __device__ __forceinline__ float b2f(uint16_t h) {
    uint32_t u = ((uint32_t)h) << 16;
    return __builtin_bit_cast(float, u);
}

__global__ __launch_bounds__(256)
void cvt_f32_bf16(const float* __restrict__ in, uint16_t* __restrict__ out, int n4) {
    int i = blockIdx.x * blockDim.x + threadIdx.x;
    if (i >= n4) return;
    float4 v = ((const float4*)in)[i];
    ushort4 o;
    o.x = f2b(v.x); o.y = f2b(v.y); o.z = f2b(v.z); o.w = f2b(v.w);
    ((ushort4*)out)[i] = o;
}

// async global->LDS, 16B per lane. LDS dest is wave-uniform base (+lane*16 in HW).
static __device__ __forceinline__ void gload16(const uint16_t* g, uint16_t* l) {
    __builtin_amdgcn_global_load_lds(
        (__attribute__((address_space(1))) void*)(uintptr_t)g,
        (__attribute__((address_space(3))) void*)(uintptr_t)l,
        16, 0, 0);
}

// ---------------- bf16 MFMA GEMM: C = epi(A @ B^T + bias) ----------------
// A: [M][K] bf16 row-major, B: [N][K] bf16 row-major, C: [M][N] bf16.
// EPI: 0 = +bias; 1 = (+bias)*scale+shift; 2 = relu(+bias)
// 256x256 tile, BK=64, 8 waves (2Mx4N), per-wave 128x64 output.
// Counted-vmcnt pipeline (T3+T4 essence), 2 barriers + vmcnt(8) per K-tile:
//   B1 (WAR: buf^1's readers done) -> stage(t+1 -> buf^1) -> vmcnt(8)
//   (own tile-t loads landed) -> B2 (RAW: ALL waves' tile-t loads landed)
//   -> compute tile t.  vmcnt never drains to 0 in the main loop.
// LDS chunk swizzle: phys16Bchunk = logical ^ (row&7), applied on BOTH the
// global source (staging) and the ds_read (involution, rule #21) -> 2-way max.
// M % 256 == 0, N % 256 == 0, K % 64 == 0 (all shapes here satisfy this).
template<int EPI>
__global__ __launch_bounds__(512, 2)
void gemm_bf16(const uint16_t* __restrict__ A, const uint16_t* __restrict__ B,
               const float* __restrict__ bias, const float* __restrict__ scale,
               const float* __restrict__ shift, uint16_t* __restrict__ C,
               int M, int N, int K, int gx)
{
    __shared__ __align__(16) uint16_t As[2][256 * 64];
    __shared__ __align__(16) uint16_t Bs[2][256 * 64];
    const int tid  = threadIdx.x;
    const int lane = tid & 63;
    const int m_   = lane & 15;
    const int kg   = lane >> 4;           // k-group 0..3 (8 bf16 each)
    const int w    = tid >> 6;
    const int wr   = w >> 2;              // 0..1
    const int wc   = w & 3;               // 0..3

    // T1 bijective XCD swizzle (nwg % 8 == 0 for all grids used here).
    const int nwg = gridDim.x;
    const int q   = nwg >> 3;
    const int wg  = (blockIdx.x & 7) * q + (blockIdx.x >> 3);
    const int m0  = (wg / gx) * 256;
    const int n0  = (wg % gx) * 256;

    f32x4 acc[8][4] = {};

    // Staging: tile = 256 rows x 64 bf16 = 2048 16B-chunks per matrix;
    // 512 threads x 4 chunks. Chunk c holds (row=c>>3, logical slot (c&7)^(row&7)).
    int srow[4], ssl[4], sbase[4];
#pragma unroll
    for (int it = 0; it < 4; ++it) {
        const int c = it * 512 + tid;
        srow[it]  = c >> 3;
        ssl[it]   = (c & 7) ^ (srow[it] & 7);
        sbase[it] = (it * 512 + (tid & 448)) * 8;   // wave-uniform 16B-chunk base
    }
    auto stage = [&](int buf, int k0) {
#pragma unroll
        for (int it = 0; it < 4; ++it)
            gload16(A + (size_t)(m0 + srow[it]) * K + k0 + ssl[it] * 8,
                    &As[buf][sbase[it]]);
#pragma unroll
        for (int it = 0; it < 4; ++it)
            gload16(B + (size_t)(n0 + srow[it]) * K + k0 + ssl[it] * 8,
                    &Bs[buf][sbase[it]]);
    };

    stage(0, 0);
    const int NT = K >> 6;
    for (int t = 0; t < NT; ++t) {
        const int buf = t & 1;
        __builtin_amdgcn_s_barrier();          // B1: buf^1 free (prev readers done)
        __builtin_amdgcn_sched_barrier(0);
        if (t + 1 < NT) {
            stage(buf ^ 1, (t + 1) << 6);
            asm volatile("s_waitcnt vmcnt(8)" ::: "memory");  // own tile-t landed
        } else {
            asm volatile("s_waitcnt vmcnt(0)" ::: "memory");
        }
        __builtin_amdgcn_s_barrier();          // B2: tile t visible to ALL waves
        __builtin_amdgcn_sched_barrier(0);

        // A fragments for this wave: rows wr*128 + i*16 + m_, full K=64.
        bf16x8 a[8][2];
#pragma unroll
        for (int i = 0; i < 8; ++i) {
            const int row = wr * 128 + i * 16 + m_;
#pragma unroll
            for (int kk = 0; kk < 2; ++kk) {
                const int ch = (kk * 4 + kg) ^ (m_ & 7);
                a[i][kk] = *reinterpret_cast<const bf16x8*>(
                    &As[buf][row * 64 + ch * 8]);
            }
        }
        // 4 phases over B column-fragments; setprio around each MFMA cluster.
#pragma unroll
        for (int j = 0; j < 4; ++j) {
            const int row = wc * 64 + j * 16 + m_;
            const bf16x8 b0 = *reinterpret_cast<const bf16x8*>(
                &Bs[buf][row * 64 + ((0 + kg) ^ (m_ & 7)) * 8]);
            const bf16x8 b1 = *reinterpret_cast<const bf16x8*>(
                &Bs[buf][row * 64 + ((4 + kg) ^ (m_ & 7)) * 8]);
            __builtin_amdgcn_s_setprio(1);
#pragma unroll
            for (int i = 0; i < 8; ++i) {
                acc[i][j] = __builtin_amdgcn_mfma_f32_16x16x32_bf16(
                    a[i][0], b0, acc[i][j], 0, 0, 0);
                acc[i][j] = __builtin_amdgcn_mfma_f32_16x16x32_bf16(
                    a[i][1], b1, acc[i][j], 0, 0, 0);
            }
            __builtin_amdgcn_s_setprio(0);
        }
    }

    // ---- epilogue: C/D layout col = lane&15, row = (lane>>4)*4 + reg ----
    const int r0 = m0 + wr * 128;
    const int c0 = n0 + wc * 64;
#pragma unroll
    for (int i = 0; i < 8; ++i) {
#pragma unroll
        for (int j = 0; j < 4; ++j) {
            const int col = c0 + j * 16 + m_;
            const float bs = bias[col];
            float sc = 0.f, sh = 0.f;
            if constexpr (EPI == 1) { sc = scale[col]; sh = shift[col]; }
#pragma unroll
            for (int r = 0; r < 4; ++r) {
                float v = acc[i][j][r] + bs;
                if constexpr (EPI == 1) v = v * sc + sh;
                if constexpr (EPI == 2) v = fmaxf(v, 0.f);
                const int rowo = r0 + i * 16 + kg * 4 + r;
                C[(size_t)rowo * N + col] = f2b(v);
            }
        }
    }
}

// ---------------- Head mixing: out[b,t,h,d] = sum_s V[b,s,h,d] * M[h,s,t] ----
__global__ __launch_bounds__(256)
void mix_heads(const uint16_t* __restrict__ V, const float* __restrict__ Mh,
               uint16_t* __restrict__ out)
{
    __shared__ float Ms[32][132];  // [s][t]
    __shared__ float Vs[32][68];   // [s][d]
    const int h = blockIdx.x, b = blockIdx.y;
    const int tid = threadIdx.x;
    const int tx = tid & 15, ty = tid >> 4;

    float acc[8][4] = {};

    const float* Mbase = Mh + (size_t)h * MSL_ * MSL_;
    const uint16_t* Vbase = V + (size_t)b * MSL_ * D_ + h * DH_;

    for (int s0 = 0; s0 < MSL_; s0 += 32) {
#pragma unroll
        for (int i = 0; i < 4; ++i) {
            const int idx = tid + i * 256;
            const int row = idx >> 5;
            const int c4  = (idx & 31) << 2;
            *(float4*)&Ms[row][c4] =
                *(const float4*)(Mbase + (size_t)(s0 + row) * MSL_ + c4);
        }
#pragma unroll
        for (int i = 0; i < 2; ++i) {
            const int idx = tid + i * 256;
            const int row = idx >> 4;
            const int c4  = (idx & 15) << 2;
            ushort4 v = *(const ushort4*)(Vbase + (size_t)(s0 + row) * D_ + c4);
            Vs[row][c4 + 0] = b2f(v.x); Vs[row][c4 + 1] = b2f(v.y);
            Vs[row][c4 + 2] = b2f(v.z); Vs[row][c4 + 3] = b2f(v.w);
        }
        __syncthreads();
#pragma unroll
        for (int s = 0; s < 32; ++s) {
            float m8[8], v4[4];
            *(float4*)&m8[0] = *(const float4*)&Ms[s][ty * 8];
            *(float4*)&m8[4] = *(const float4*)&Ms[s][ty * 8 + 4];
            *(float4*)&v4[0] = *(const float4*)&Vs[s][tx * 4];
#pragma unroll
            for (int i = 0; i < 8; ++i)
#pragma unroll
                for (int j = 0; j < 4; ++j)
                    acc[i][j] += m8[i] * v4[j];
        }
        __syncthreads();
    }

    uint16_t* obase = out + (size_t)b * MSL_ * D_ + h * DH_ + tx * 4;
#pragma unroll
    for (int i = 0; i < 8; ++i) {
        ushort4 o;
        o.x = f2b(acc[i][0]); o.y = f2b(acc[i][1]);
        o.z = f2b(acc[i][2]); o.w = f2b(acc[i][3]);
        *(ushort4*)(obase + (size_t)(ty * 8 + i) * D_) = o;
    }
}

// ---------------- Classifier ----------------
__global__ void cls_kernel(const uint16_t* __restrict__ H, const float* __restrict__ W,
                           const float* __restrict__ bias, float* __restrict__ out)
{
    const int b = blockIdx.x;
    const int lane = threadIdx.x;
    const uint16_t* row = H + (size_t)b * MSL_ * D_;
    float s0 = 0.f, s1 = 0.f;
    for (int d = lane; d < D_; d += 64) {
        const float xv = b2f(row[d]);
        s0 += xv * W[d];
        s1 += xv * W[D_ + d];
    }
#pragma unroll
    for (int off = 32; off > 0; off >>= 1) {
        s0 += __shfl_down(s0, off);
        s1 += __shfl_down(s1, off);
    }
    if (lane == 0) {
        out[b * 2 + 0] = s0 + bias[0];
        out[b * 2 + 1] = s1 + bias[1];
    }
}

extern "C" void kernel_launch(void* const* d_in, const int* in_sizes, int n_in,
                              void* d_out, int out_size, void* d_ws, size_t ws_size,
                              hipStream_t stream)
{
    const float* x     = (const float*)d_in[0];
    const float* M0    = (const float*)d_in[1];
    const float* M1    = (const float*)d_in[2];
    const float* Wv_w  = (const float*)d_in[3];
    const float* Wv_b  = (const float*)d_in[4];
    const float* d0_w  = (const float*)d_in[5];
    const float* d0_b  = (const float*)d_in[6];
    const float* lnw   = (const float*)d_in[7];
    const float* lnb   = (const float*)d_in[8];
    const float* ff0_w = (const float*)d_in[9];
    const float* ff0_b = (const float*)d_in[10];
    const float* ff1_w = (const float*)d_in[11];
    const float* ff1_b = (const float*)d_in[12];
    const float* lnffw = (const float*)d_in[13];
    const float* lnffb = (const float*)d_in[14];
    const float* Wv1_w = (const float*)d_in[15];
    const float* Wv1_b = (const float*)d_in[16];
    const float* d01_w = (const float*)d_in[17];
    const float* d01_b = (const float*)d_in[18];
    const float* lnw1  = (const float*)d_in[19];
    const float* lnb1  = (const float*)d_in[20];
    const float* ff01_w = (const float*)d_in[21];
    const float* ff01_b = (const float*)d_in[22];
    const float* ff11_w = (const float*)d_in[23];
    const float* ff11_b = (const float*)d_in[24];
    const float* lnffw1 = (const float*)d_in[25];
    const float* lnffb1 = (const float*)d_in[26];
    const float* cls_w  = (const float*)d_in[27];
    const float* cls_b  = (const float*)d_in[28];

    // ---- workspace layout (ushort elements) ----
    const size_t NB = (size_t)ROWS_ * D_;           // 12,582,912
    const size_t WTOT = 2ull * (2ull * D_ * D_ + 2ull * DI_ * D_);  // 11,796,480
    uint16_t* A0 = (uint16_t*)d_ws;
    uint16_t* A1 = A0 + NB;
    uint16_t* A2 = A1 + NB;
    uint16_t* wp = A2 + NB;
    uint16_t* bWv[2], *bD0[2], *bF0[2], *bF1[2];
    for (int blk = 0; blk < 2; ++blk) {
        bWv[blk] = wp; wp += (size_t)D_ * D_;
        bD0[blk] = wp; wp += (size_t)D_ * D_;
        bF0[blk] = wp; wp += (size_t)DI_ * D_;
        bF1[blk] = wp; wp += (size_t)D_ * DI_;
    }
    const size_t used_alias = (3ull * NB + WTOT) * sizeof(uint16_t);
    const size_t need_full  = used_alias + 4ull * NB * sizeof(uint16_t);
    const bool full = (ws_size >= need_full);
    uint16_t* F = full ? wp : A0;                   // FULL: dedicated; ALIAS: [A0;A1]
    const int CH = full ? ROWS_ : (ROWS_ / 2);      // 16384 or 8192 (both %256==0)

    auto cvt = [&](const float* in, uint16_t* out, size_t n) {
        const int n4 = (int)(n / 4);
        cvt_f32_bf16<<<dim3((n4 + 255) / 256), dim3(256), 0, stream>>>(in, out, n4);
    };

    cvt(x, A2, NB);
    cvt(Wv_w,  bWv[0], (size_t)D_ * D_);
    cvt(d0_w,  bD0[0], (size_t)D_ * D_);
    cvt(ff0_w, bF0[0], (size_t)DI_ * D_);
    cvt(ff1_w, bF1[0], (size_t)D_ * DI_);
    cvt(Wv1_w, bWv[1], (size_t)D_ * D_);
    cvt(d01_w, bD0[1], (size_t)D_ * D_);
    cvt(ff01_w, bF0[1], (size_t)DI_ * D_);
    cvt(ff11_w, bF1[1], (size_t)D_ * DI_);

    const dim3 blk256(256);
    const dim3 blk512(512);

    auto gemm = [&](int EPI, const uint16_t* Ain, const uint16_t* Bw,
                    const float* bias, const float* sc, const float* sh,
                    uint16_t* Cout, int M, int N, int K) {
        const int gx = N / 256;
        const dim3 grid(gx * (M / 256));
        if (EPI == 0)
            gemm_bf16<0><<<grid, blk512, 0, stream>>>(Ain, Bw, bias, sc, sh, Cout, M, N, K, gx);
        else if (EPI == 1)
            gemm_bf16<1><<<grid, blk512, 0, stream>>>(Ain, Bw, bias, sc, sh, Cout, M, N, K, gx);
        else
            gemm_bf16<2><<<grid, blk512, 0, stream>>>(Ain, Bw, bias, sc, sh, Cout, M, N, K, gx);
    };

    // Per transformer block (input & output = A2):
    //   V: A2->A0 ; mix: A0->A1 ; dense0: A1->A2 ; FFN chunks on A2 (A0,A1 dead).
    auto run_block = [&](const float* Mm, int bi,
                         const float* wv_b, const float* db,
                         const float* lw, const float* lb,
                         const float* f0b, const float* f1b,
                         const float* lfw, const float* lfb) {
        gemm(0, A2, bWv[bi], wv_b, nullptr, nullptr, A0, ROWS_, D_, D_);
        mix_heads<<<dim3(NH_, BS_), blk256, 0, stream>>>(A0, Mm, A1);
        gemm(1, A1, bD0[bi], db, lw, lb, A2, ROWS_, D_, D_);
        for (int c = 0; c < ROWS_; c += CH) {
            gemm(2, A2 + (size_t)c * D_, bF0[bi], f0b, nullptr, nullptr, F, CH, DI_, D_);
            gemm(1, F, bF1[bi], f1b, lfw, lfb, A2 + (size_t)c * D_, CH, D_, DI_);
        }
    };

    run_block(M0, 0, Wv_b, d0_b, lnw, lnb, ff0_b, ff1_b, lnffw, lnffb);
    run_block(M1, 1, Wv1_b, d01_b, lnw1, lnb1, ff01_b, ff11_b, lnffw1, lnffb1);

    cls_kernel<<<dim3(BS_), dim3(64), 0, stream>>>(A2, cls_w, cls_b, (float*)d_out);
}